// Round 3
// baseline (79253.705 us; speedup 1.0000x reference)
//
#include <hip/hip_runtime.h>
#include <hip/hip_cooperative_groups.h>
#include <cmath>

namespace cg = cooperative_groups;

#define BATCH 128
#define TLEN  256
#define HDIM  1024
#define CDIM  10
#define NT    256
#define NWG   256

// h state, double buffered, k-major: g_h[buf][j][b]
__device__ float g_h[2][HDIM][BATCH];

__device__ __forceinline__ float4 ld4(const float* p) { return *(const float4*)p; }
__device__ __forceinline__ float Qc(const float4& v, int i) {
    switch (i) { case 0: return v.x; case 1: return v.y; case 2: return v.z; default: return v.w; }
}
#define FMA4(d, s, v) do { (d).x = fmaf((s), (v).x, (d).x); (d).y = fmaf((s), (v).y, (d).y); \
                           (d).z = fmaf((s), (v).z, (d).z); (d).w = fmaf((s), (v).w, (d).w); } while (0)

// Block tile: 8 j (rows 32 = 4 gates x 8 j) x 64 b, k=1024 split 8-way across lane bits.
// Thread: wave=jp (j-pair), lane = (bs<<3)|ks; owns rows {g*8 + jp*2 + jl} x b-octet bs,
// k-slice {c*32 + kk*8 + ks}. Reduction over ks via shfl_xor butterfly (no LDS scratch).
__global__ void __launch_bounds__(NT, 1)
lstm_fused(const float* __restrict__ x,
           const float* __restrict__ Wgx, const float* __restrict__ Wgh, const float* __restrict__ bg,
           const float* __restrict__ Wix, const float* __restrict__ Wih, const float* __restrict__ bi,
           const float* __restrict__ Wfx, const float* __restrict__ Wfh, const float* __restrict__ bf,
           const float* __restrict__ Wox, const float* __restrict__ Woh, const float* __restrict__ bo,
           const float* __restrict__ Wph, const float* __restrict__ bp,
           float* __restrict__ out)
{
    // LDS: W persistent 32x1028 (131584 B) + h dbuf 2x32x68 (17408 B) + sX (256 B) = 149248 B
    __shared__ float sWl[32][1028];   // [row=g*8+jl8][c*32 + swizzled slot]; pad 4 -> row bank offset +4
    __shared__ float sH[2][32][68];   // [buf][kc][b], pad 68 -> kc bank offset +4
    __shared__ float sX[64];

    const int tid  = threadIdx.x;
    const int jp   = tid >> 6;          // wave id = j-pair (0..3)
    const int lane = tid & 63;
    const int ks   = lane & 7;          // k-slice (0..7)
    const int bs   = lane >> 3;         // b-octet (0..7)
    const int rgB  = blockIdx.x >> 1;   // j-group: j in [8*rgB, 8*rgB+8)
    const int bgB  = blockIdx.x & 1;    // b-half:  b in [64*bgB, 64*bgB+64)

    const float* Whs[4] = {Wgh, Wih, Wfh, Woh};

    // ---- stage W once, k-swizzled: element (row, global k=c*32+kc) -> slot c*32 + (kc&7)*4 + (kc>>3)
    // so thread ks's 4 chunk-elements (kc = kk*8+ks, kk=0..3) are contiguous -> aligned b128 reads.
    for (int it = 0; it < 32; ++it) {
        const int f4  = it * NT + tid;        // 0..8191 float4s
        const int row = f4 >> 8;              // 0..31
        const int k   = (f4 & 255) * 4;       // 0..1020
        const int g   = row >> 3, jl8 = row & 7;
        const float4 v = ld4(Whs[g] + (size_t)(rgB * 8 + jl8) * HDIM + k);
        const int c = k >> 5;
        #pragma unroll
        for (int e = 0; e < 4; ++e) {
            const int kc = (k & 31) + e;
            sWl[row][c * 32 + (kc & 7) * 4 + (kc >> 3)] =
                (e == 0 ? v.x : e == 1 ? v.y : e == 2 ? v.z : v.w);
        }
    }

    // ---- epilogue per-lane constants: lane computes cells (jl_c, b = bs*8 + 2*bq + {0,1})
    const int jl_c = ks >> 2;
    const int bq   = ks & 3;
    const int jc   = rgB * 8 + jp * 2 + jl_c;      // this lane's hidden unit
    const float wxc[4] = {Wgx[jc], Wix[jc], Wfx[jc], Wox[jc]};
    const float bc[4]  = {bg[jc], bi[jc], bf[jc], bo[jc]};
    float c0 = 0.f, c1 = 0.f;

    // zero h0
    {
        float2* z = (float2*)&g_h[0][0][0];
        z[(size_t)blockIdx.x * 256 + tid] = make_float2(0.f, 0.f);
    }

    cg::grid_group grid = cg::this_grid();
    __threadfence();
    grid.sync();

    // h staging roles
    const int skc = tid >> 3;            // kc 0..31
    const int sb  = (tid & 7) * 8;       // b offset 0..56

    for (int t = 0; t < TLEN; ++t) {
        const float* ghc = &g_h[t & 1][0][0];
        float*       ghn = &g_h[(t + 1) & 1][0][0];

        if (tid < 64) sX[tid] = x[(size_t)(bgB * 64 + tid) * TLEN + t];
        {   // stage h chunk 0
            const float* src = ghc + (size_t)skc * BATCH + bgB * 64 + sb;
            *(float4*)&sH[0][skc][sb]     = ld4(src);
            *(float4*)&sH[0][skc][sb + 4] = ld4(src + 4);
        }
        __syncthreads();

        float4 acc4[4][2][2];   // [gate][jl][bhalf]
        #pragma unroll
        for (int g = 0; g < 4; ++g)
            #pragma unroll
            for (int jl = 0; jl < 2; ++jl) {
                acc4[g][jl][0] = make_float4(0.f, 0.f, 0.f, 0.f);
                acc4[g][jl][1] = make_float4(0.f, 0.f, 0.f, 0.f);
            }

        #pragma unroll 1
        for (int c = 0; c < 32; ++c) {
            const int buf = c & 1;
            float4 p0, p1;
            if (c < 31) {   // global->reg prefetch of chunk c+1
                const float* src = ghc + (size_t)((c + 1) * 32 + skc) * BATCH + bgB * 64 + sb;
                p0 = ld4(src); p1 = ld4(src + 4);
            }
            // W fragments: 8 aligned b128, banks spread by ks*16B (conflict-free broadcast x8)
            float4 wf[4][2];
            #pragma unroll
            for (int g = 0; g < 4; ++g)
                #pragma unroll
                for (int jl = 0; jl < 2; ++jl)
                    wf[g][jl] = ld4(&sWl[g * 8 + jp * 2 + jl][c * 32 + ks * 4]);
            #pragma unroll
            for (int kk = 0; kk < 4; ++kk) {
                const float4 hA = ld4(&sH[buf][kk * 8 + ks][bs * 8]);
                const float4 hB = ld4(&sH[buf][kk * 8 + ks][bs * 8 + 4]);
                #pragma unroll
                for (int g = 0; g < 4; ++g)
                    #pragma unroll
                    for (int jl = 0; jl < 2; ++jl) {
                        const float w = Qc(wf[g][jl], kk);
                        FMA4(acc4[g][jl][0], w, hA);
                        FMA4(acc4[g][jl][1], w, hB);
                    }
            }
            if (c < 31) {   // reg->LDS for chunk c+1
                *(float4*)&sH[buf ^ 1][skc][sb]     = p0;
                *(float4*)&sH[buf ^ 1][skc][sb + 4] = p1;
            }
            __syncthreads();
        }

        // ---- reduce over ks (lane bits 0..2) via butterfly: deterministic pairwise tree
        #pragma unroll
        for (int g = 0; g < 4; ++g)
            #pragma unroll
            for (int jl = 0; jl < 2; ++jl)
                #pragma unroll
                for (int p = 0; p < 2; ++p) {
                    float4& v = acc4[g][jl][p];
                    #pragma unroll
                    for (int m = 1; m <= 4; m <<= 1) {
                        v.x += __shfl_xor(v.x, m);
                        v.y += __shfl_xor(v.y, m);
                        v.z += __shfl_xor(v.z, m);
                        v.w += __shfl_xor(v.w, m);
                    }
                }

        // ---- epilogue: each lane handles 2 cells (jl_c, b = bs*8 + 2bq + {0,1})
        const float xa = sX[bs * 8 + bq * 2];
        const float xb = sX[bs * 8 + bq * 2 + 1];
        float pr[4][2];
        #pragma unroll
        for (int g = 0; g < 4; ++g) {
            const float4& va = acc4[g][jl_c][bq >> 1];
            const int e = (bq & 1) * 2;
            pr[g][0] = Qc(va, e)     + xa * wxc[g] + bc[g];
            pr[g][1] = Qc(va, e + 1) + xb * wxc[g] + bc[g];
        }
        float hv0, hv1;
        {
            const float gg = tanhf(pr[0][0]);
            const float ii = 1.f / (1.f + expf(-pr[1][0]));
            const float ff = 1.f / (1.f + expf(-pr[2][0]));
            const float oo = 1.f / (1.f + expf(-pr[3][0]));
            c0 = gg * ii + c0 * ff;
            hv0 = tanhf(c0) * oo;
        }
        {
            const float gg = tanhf(pr[0][1]);
            const float ii = 1.f / (1.f + expf(-pr[1][1]));
            const float ff = 1.f / (1.f + expf(-pr[2][1]));
            const float oo = 1.f / (1.f + expf(-pr[3][1]));
            c1 = gg * ii + c1 * ff;
            hv1 = tanhf(c1) * oo;
        }
        *(float2*)(ghn + (size_t)jc * BATCH + bgB * 64 + bs * 8 + bq * 2) = make_float2(hv0, hv1);

        __threadfence();
        grid.sync();
    } // t

    // ---- final projection: out = h_final @ W_ph + bias_p (final h in buf 0; round-1-verified path)
    if (blockIdx.x < BATCH) {
        const int b = blockIdx.x;
        float part[CDIM];
        #pragma unroll
        for (int c2 = 0; c2 < CDIM; ++c2) part[c2] = 0.f;
        const float* hfin = &g_h[0][0][0];
        for (int k = tid; k < HDIM; k += NT) {
            const float hvv = hfin[(size_t)k * BATCH + b];
            #pragma unroll
            for (int c2 = 0; c2 < CDIM; ++c2)
                part[c2] = fmaf(hvv, Wph[(size_t)k * CDIM + c2], part[c2]);
        }
        float* red = (float*)&sH[0][0][0];   // reuse dead staging LDS: 256*12*4 = 12 KB
        #pragma unroll
        for (int c2 = 0; c2 < CDIM; ++c2) red[tid * 12 + c2] = part[c2];
        __syncthreads();
        for (int s = NT / 2; s > 0; s >>= 1) {
            if (tid < s) {
                #pragma unroll
                for (int c2 = 0; c2 < CDIM; ++c2)
                    red[tid * 12 + c2] += red[(tid + s) * 12 + c2];
            }
            __syncthreads();
        }
        if (tid < CDIM) out[(size_t)b * CDIM + tid] = red[tid] + bp[tid];
    }
}

extern "C" void kernel_launch(void* const* d_in, const int* in_sizes, int n_in,
                              void* d_out, int out_size, void* d_ws, size_t ws_size,
                              hipStream_t stream) {
    const float* x   = (const float*)d_in[0];
    const float* Wgx = (const float*)d_in[1];
    const float* Wgh = (const float*)d_in[2];
    const float* bg  = (const float*)d_in[3];
    const float* Wix = (const float*)d_in[4];
    const float* Wih = (const float*)d_in[5];
    const float* bi  = (const float*)d_in[6];
    const float* Wfx = (const float*)d_in[7];
    const float* Wfh = (const float*)d_in[8];
    const float* bf  = (const float*)d_in[9];
    const float* Wox = (const float*)d_in[10];
    const float* Woh = (const float*)d_in[11];
    const float* bo  = (const float*)d_in[12];
    const float* Wph = (const float*)d_in[13];
    const float* bp  = (const float*)d_in[14];
    float* out = (float*)d_out;

    void* args[] = {&x, &Wgx, &Wgh, &bg, &Wix, &Wih, &bi, &Wfx, &Wfh, &bf,
                    &Wox, &Woh, &bo, &Wph, &bp, &out};
    hipLaunchCooperativeKernel((void*)lstm_fused, dim3(NWG), dim3(NT),
                               args, 0, stream);
}

// Round 4
// 21213.863 us; speedup vs baseline: 3.7359x; 3.7359x over previous
//
#include <hip/hip_runtime.h>
#include <hip/hip_cooperative_groups.h>
#include <cmath>

namespace cg = cooperative_groups;

#define BATCH 128
#define TLEN  256
#define HDIM  1024
#define CDIM  10
#define NT    256
#define NWG   256

// h state, double buffered, k-major: g_h[buf][j][b]
__device__ float g_h[2][HDIM][BATCH];

__device__ __forceinline__ float4 ld4(const float* p) { return *(const float4*)p; }

#define FMA4(d, s, v) do { (d).x = fmaf((s), (v).x, (d).x); (d).y = fmaf((s), (v).y, (d).y); \
                           (d).z = fmaf((s), (v).z, (d).z); (d).w = fmaf((s), (v).w, (d).w); } while (0)

// Block: 8 j x 64 b. Thread: wave jq -> j pair {jq*2, jq*2+1}; lane = bo8*8+ks;
// bo8 -> b octet, ks -> 8-way k-slice (k = c*32 + kk*8 + ks). Gates live in float4
// components (x=g, y=i, z=f, w=o). ALL register-array indices are compile-time
// constants (round-3 lesson: one dynamic index -> whole acc array demoted to
// scratch -> 60 GB of HBM traffic).
__global__ void __launch_bounds__(NT, 1)
lstm_fused(const float* __restrict__ x,
           const float* __restrict__ Wgx, const float* __restrict__ Wgh, const float* __restrict__ bg,
           const float* __restrict__ Wix, const float* __restrict__ Wih, const float* __restrict__ bi,
           const float* __restrict__ Wfx, const float* __restrict__ Wfh, const float* __restrict__ bf,
           const float* __restrict__ Wox, const float* __restrict__ Woh, const float* __restrict__ bo,
           const float* __restrict__ Wph, const float* __restrict__ bp,
           float* __restrict__ out)
{
    // LDS: W gate-interleaved 8x1024x4 (128 KB) + h dbuf 2x32x68 (17 KB) + sX
    __shared__ float sW[8][HDIM][4];   // [j_local][k][gate]
    __shared__ float sH[2][32][68];    // [buf][k_chunk][b_local], pad to 68
    __shared__ float sX[64];

    const int tid  = threadIdx.x;
    const int jq   = tid >> 6;          // wave id: j-pair index (0..3)
    const int lane = tid & 63;
    const int ks   = lane & 7;          // k-slice (0..7)
    const int bo8  = lane >> 3;         // b-octet (0..7)
    const int rgB  = blockIdx.x >> 1;   // j-group: j in [8*rgB, 8*rgB+8)
    const int bgB  = blockIdx.x & 1;    // b-half:  b in [64*bgB, 64*bgB+64)

    // ---- stage W once, gate-interleaved (one-time bank conflicts are fine) ----
    {
        auto stageW = [&](const float* Wsrc, int g) {
            #pragma unroll
            for (int it = 0; it < 8; ++it) {
                const float4 v = ld4(Wsrc + (size_t)(rgB * 8 + it) * HDIM + tid * 4);
                sW[it][tid * 4 + 0][g] = v.x;
                sW[it][tid * 4 + 1][g] = v.y;
                sW[it][tid * 4 + 2][g] = v.z;
                sW[it][tid * 4 + 3][g] = v.w;
            }
        };
        stageW(Wgh, 0); stageW(Wih, 1); stageW(Wfh, 2); stageW(Woh, 3);
    }

    // ---- epilogue per-thread constants: thread's 2 cells are
    //      (j = rgB*8 + jq*2 + (ks>>2),  b = bgB*64 + bo8*8 + (ks&3)*2 + {0,1})
    const int jc = rgB * 8 + jq * 2 + (ks >> 2);
    const float4 wx4 = make_float4(Wgx[jc], Wix[jc], Wfx[jc], Wox[jc]);
    const float4 b4  = make_float4(bg[jc], bi[jc], bf[jc], bo[jc]);
    float c0 = 0.f, c1 = 0.f;

    // zero h0 (grid exactly covers g_h[0])
    {
        float2* z = (float2*)&g_h[0][0][0];
        z[(size_t)blockIdx.x * 256 + tid] = make_float2(0.f, 0.f);
    }

    cg::grid_group grid = cg::this_grid();
    __threadfence();
    grid.sync();

    const int skc = tid >> 3;            // staging: k within chunk (0..31)
    const int sb  = (tid & 7) * 8;       // staging: b offset (0..56)

    for (int t = 0; t < TLEN; ++t) {
        const float* ghc = &g_h[t & 1][0][0];
        float*       ghn = &g_h[(t + 1) & 1][0][0];

        if (tid < 64) sX[tid] = x[(size_t)(bgB * 64 + tid) * TLEN + t];
        {   // stage h chunk 0
            const float* src = ghc + (size_t)skc * BATCH + bgB * 64 + sb;
            *(float4*)&sH[0][skc][sb]     = ld4(src);
            *(float4*)&sH[0][skc][sb + 4] = ld4(src + 4);
        }
        __syncthreads();

        float4 acc[2][8];   // [j_local][b_local]; components = 4 gates. STATIC indices only.
        #pragma unroll
        for (int jl = 0; jl < 2; ++jl)
            #pragma unroll
            for (int cb = 0; cb < 8; ++cb)
                acc[jl][cb] = make_float4(0.f, 0.f, 0.f, 0.f);

        #pragma unroll 1
        for (int c = 0; c < 32; ++c) {
            const int buf = c & 1;
            float4 p0, p1;
            if (c < 31) {   // global->reg prefetch of chunk c+1
                const float* src = ghc + (size_t)((c + 1) * 32 + skc) * BATCH + bgB * 64 + sb;
                p0 = ld4(src); p1 = ld4(src + 4);
            }
            #pragma unroll
            for (int kk = 0; kk < 4; ++kk) {
                const int kc = kk * 8 + ks;
                // W: lane addrs differ only in ks -> 8 distinct bank-quads, conflict-free
                const float4 w0 = ld4(&sW[jq * 2 + 0][c * 32 + kc][0]);
                const float4 w1 = ld4(&sW[jq * 2 + 1][c * 32 + kc][0]);
                const float4 hA = ld4(&sH[buf][kc][bo8 * 8]);
                const float4 hB = ld4(&sH[buf][kc][bo8 * 8 + 4]);
                FMA4(acc[0][0], hA.x, w0); FMA4(acc[0][1], hA.y, w0);
                FMA4(acc[0][2], hA.z, w0); FMA4(acc[0][3], hA.w, w0);
                FMA4(acc[0][4], hB.x, w0); FMA4(acc[0][5], hB.y, w0);
                FMA4(acc[0][6], hB.z, w0); FMA4(acc[0][7], hB.w, w0);
                FMA4(acc[1][0], hA.x, w1); FMA4(acc[1][1], hA.y, w1);
                FMA4(acc[1][2], hA.z, w1); FMA4(acc[1][3], hA.w, w1);
                FMA4(acc[1][4], hB.x, w1); FMA4(acc[1][5], hB.y, w1);
                FMA4(acc[1][6], hB.z, w1); FMA4(acc[1][7], hB.w, w1);
            }
            if (c < 31) {   // reg->LDS for chunk c+1
                *(float4*)&sH[buf ^ 1][skc][sb]     = p0;
                *(float4*)&sH[buf ^ 1][skc][sb + 4] = p1;
            }
            __syncthreads();
        }

        // ---- butterfly over ks (lane bits 0..2): deterministic pairwise tree
        #pragma unroll
        for (int jl = 0; jl < 2; ++jl)
            #pragma unroll
            for (int cb = 0; cb < 8; ++cb) {
                float4& v = acc[jl][cb];
                v.x += __shfl_xor(v.x, 1); v.y += __shfl_xor(v.y, 1);
                v.z += __shfl_xor(v.z, 1); v.w += __shfl_xor(v.w, 1);
                v.x += __shfl_xor(v.x, 2); v.y += __shfl_xor(v.y, 2);
                v.z += __shfl_xor(v.z, 2); v.w += __shfl_xor(v.w, 2);
                v.x += __shfl_xor(v.x, 4); v.y += __shfl_xor(v.y, 4);
                v.z += __shfl_xor(v.z, 4); v.w += __shfl_xor(v.w, 4);
            }

        // ---- epilogue: 8 static branches; all register indices literal constants
#define EPI(K)                                                                              \
        if (ks == (K)) {                                                                    \
            const int cbK = ((K) & 3) * 2;                                                  \
            float4 q0 = acc[(K) >> 2][((K) & 3) * 2 + 0];                                   \
            float4 q1 = acc[(K) >> 2][((K) & 3) * 2 + 1];                                   \
            const float xa = sX[bo8 * 8 + cbK];                                             \
            const float xb = sX[bo8 * 8 + cbK + 1];                                         \
            FMA4(q0, xa, wx4); FMA4(q1, xb, wx4);                                           \
            q0.x += b4.x; q0.y += b4.y; q0.z += b4.z; q0.w += b4.w;                         \
            q1.x += b4.x; q1.y += b4.y; q1.z += b4.z; q1.w += b4.w;                         \
            const float g0 = tanhf(q0.x);                                                   \
            const float i0 = 1.f / (1.f + expf(-q0.y));                                     \
            const float f0 = 1.f / (1.f + expf(-q0.z));                                     \
            const float o0 = 1.f / (1.f + expf(-q0.w));                                     \
            c0 = g0 * i0 + c0 * f0;                                                         \
            const float hv0 = tanhf(c0) * o0;                                               \
            const float g1 = tanhf(q1.x);                                                   \
            const float i1 = 1.f / (1.f + expf(-q1.y));                                     \
            const float f1 = 1.f / (1.f + expf(-q1.z));                                     \
            const float o1 = 1.f / (1.f + expf(-q1.w));                                     \
            c1 = g1 * i1 + c1 * f1;                                                         \
            const float hv1 = tanhf(c1) * o1;                                               \
            *(float2*)(ghn + (size_t)jc * BATCH + bgB * 64 + bo8 * 8 + cbK) =               \
                make_float2(hv0, hv1);                                                      \
        }
        EPI(0) EPI(1) EPI(2) EPI(3) EPI(4) EPI(5) EPI(6) EPI(7)
#undef EPI

        __threadfence();
        grid.sync();
    } // t

    // ---- final projection: out = h_final @ W_ph + bias_p (final h in buf 0)
    if (blockIdx.x < BATCH) {
        const int b = blockIdx.x;
        float part[CDIM];
        #pragma unroll
        for (int c2 = 0; c2 < CDIM; ++c2) part[c2] = 0.f;
        const float* hfin = &g_h[0][0][0];
        for (int k = tid; k < HDIM; k += NT) {
            const float hvv = hfin[(size_t)k * BATCH + b];
            #pragma unroll
            for (int c2 = 0; c2 < CDIM; ++c2)
                part[c2] = fmaf(hvv, Wph[(size_t)k * CDIM + c2], part[c2]);
        }
        float* red = (float*)&sH[0][0][0];   // reuse dead staging LDS
        #pragma unroll
        for (int c2 = 0; c2 < CDIM; ++c2) red[tid * 12 + c2] = part[c2];
        __syncthreads();
        for (int s = NT / 2; s > 0; s >>= 1) {
            if (tid < s) {
                #pragma unroll
                for (int c2 = 0; c2 < CDIM; ++c2)
                    red[tid * 12 + c2] += red[(tid + s) * 12 + c2];
            }
            __syncthreads();
        }
        if (tid < CDIM) out[(size_t)b * CDIM + tid] = red[tid] + bp[tid];
    }
}

extern "C" void kernel_launch(void* const* d_in, const int* in_sizes, int n_in,
                              void* d_out, int out_size, void* d_ws, size_t ws_size,
                              hipStream_t stream) {
    const float* x   = (const float*)d_in[0];
    const float* Wgx = (const float*)d_in[1];
    const float* Wgh = (const float*)d_in[2];
    const float* bg  = (const float*)d_in[3];
    const float* Wix = (const float*)d_in[4];
    const float* Wih = (const float*)d_in[5];
    const float* bi  = (const float*)d_in[6];
    const float* Wfx = (const float*)d_in[7];
    const float* Wfh = (const float*)d_in[8];
    const float* bf  = (const float*)d_in[9];
    const float* Wox = (const float*)d_in[10];
    const float* Woh = (const float*)d_in[11];
    const float* bo  = (const float*)d_in[12];
    const float* Wph = (const float*)d_in[13];
    const float* bp  = (const float*)d_in[14];
    float* out = (float*)d_out;

    void* args[] = {&x, &Wgx, &Wgh, &bg, &Wix, &Wih, &bi, &Wfx, &Wfh, &bf,
                    &Wox, &Woh, &bo, &Wph, &bp, &out};
    hipLaunchCooperativeKernel((void*)lstm_fused, dim3(NWG), dim3(NT),
                               args, 0, stream);
}

// Round 6
// 12821.748 us; speedup vs baseline: 6.1812x; 1.6545x over previous
//
#include <hip/hip_runtime.h>
#include <cmath>

#define BATCH 128
#define TLEN  256
#define HDIM  1024
#define CDIM  10
#define NT    256
#define NWG   256

typedef unsigned long long u64;
typedef unsigned int u32;

// h state, double buffered, k-major, stored natively as u64 (2 packed floats):
// g_hx[buf][j][b/2]. ALL accesses are relaxed agent-scope atomics (sc1: bypass
// the non-coherent per-XCD L2) -> no buffer_wbl2/buffer_inv fences needed, ever.
__device__ u64 g_hx[2][HDIM][BATCH / 2];

__device__ __forceinline__ float4 ld4(const float* p) { return *(const float4*)p; }

__device__ __forceinline__ u64 aload(const u64* p) {
    return __hip_atomic_load(p, __ATOMIC_RELAXED, __HIP_MEMORY_SCOPE_AGENT);
}
__device__ __forceinline__ void astore(u64* p, u64 v) {
    __hip_atomic_store(p, v, __ATOMIC_RELAXED, __HIP_MEMORY_SCOPE_AGENT);
}
__device__ __forceinline__ float4 two2f4(u64 a, u64 b) {
    u64 t[2] = {a, b}; float4 f; __builtin_memcpy(&f, t, 16); return f;
}
__device__ __forceinline__ u64 f2toU(float a, float b) {
    float2 f = make_float2(a, b); u64 v; __builtin_memcpy(&v, &f, 8); return v;
}
__device__ __forceinline__ float2 u2f2(u64 v) {
    float2 f; __builtin_memcpy(&f, &v, 8); return f;
}

// Grid barrier, fence-free. __syncthreads drains vmcnt(0), so this block's sc1
// h-stores are at the coherence point before the arrive. Spin is bounded: a
// logic bug degrades to a wrong answer, never a harness hang.
__device__ __forceinline__ void gbar(u32* ctr, int slot) {
    __syncthreads();
    if (threadIdx.x == 0) {
        __hip_atomic_fetch_add(&ctr[slot], 1u, __ATOMIC_RELAXED, __HIP_MEMORY_SCOPE_AGENT);
        int guard = 0;
        while (__hip_atomic_load(&ctr[slot], __ATOMIC_RELAXED, __HIP_MEMORY_SCOPE_AGENT) < NWG
               && ++guard < (1 << 22)) {
            __builtin_amdgcn_s_sleep(2);
        }
    }
    __syncthreads();
}

#define FMA4(d, s, v) do { (d).x = fmaf((s), (v).x, (d).x); (d).y = fmaf((s), (v).y, (d).y); \
                           (d).z = fmaf((s), (v).z, (d).z); (d).w = fmaf((s), (v).w, (d).w); } while (0)

// Block: 8 j x 64 b. Thread: wave jq -> j pair; lane = bo8*8+ks. Gates in
// float4 components (x=g,y=i,z=f,w=o). All register-array indices static.
__global__ void __launch_bounds__(NT, 1)
lstm_fused(const float* __restrict__ x,
           const float* __restrict__ Wgx, const float* __restrict__ Wgh, const float* __restrict__ bg,
           const float* __restrict__ Wix, const float* __restrict__ Wih, const float* __restrict__ bi,
           const float* __restrict__ Wfx, const float* __restrict__ Wfh, const float* __restrict__ bf,
           const float* __restrict__ Wox, const float* __restrict__ Woh, const float* __restrict__ bo,
           const float* __restrict__ Wph, const float* __restrict__ bp,
           u32* __restrict__ bar, float* __restrict__ out)
{
    __shared__ float sW[8][HDIM][4];   // [j_local][k][gate], 128 KB, persistent
    __shared__ float sH[2][32][68];    // [buf][k_chunk][b_local]
    __shared__ float sX[64];

    const int tid  = threadIdx.x;
    const int jq   = tid >> 6;
    const int lane = tid & 63;
    const int ks   = lane & 7;
    const int bo8  = lane >> 3;
    const int rgB  = blockIdx.x >> 1;   // j in [8*rgB, 8*rgB+8)
    const int bgB  = blockIdx.x & 1;    // b in [64*bgB, 64*bgB+64)

    // ---- stage W once, gate-interleaved ----
    {
        auto stageW = [&](const float* Wsrc, int g) {
            #pragma unroll
            for (int it = 0; it < 8; ++it) {
                const float4 v = ld4(Wsrc + (size_t)(rgB * 8 + it) * HDIM + tid * 4);
                sW[it][tid * 4 + 0][g] = v.x;
                sW[it][tid * 4 + 1][g] = v.y;
                sW[it][tid * 4 + 2][g] = v.z;
                sW[it][tid * 4 + 3][g] = v.w;
            }
        };
        stageW(Wgh, 0); stageW(Wih, 1); stageW(Wfh, 2); stageW(Woh, 3);
    }

    // thread's 2 cells: (j = rgB*8 + jq*2 + (ks>>2), b = bgB*64 + bo8*8 + (ks&3)*2 + {0,1})
    const int jc = rgB * 8 + jq * 2 + (ks >> 2);
    const float4 wx4 = make_float4(Wgx[jc], Wix[jc], Wfx[jc], Wox[jc]);
    const float4 b4  = make_float4(bg[jc], bi[jc], bf[jc], bo[jc]);
    float c0 = 0.f, c1 = 0.f;

    // zero h0: 256 blocks x 256 threads x 1 u64 == 1024*64 u64 == g_hx[0]
    astore(&g_hx[0][0][0] + (size_t)blockIdx.x * 256 + tid, 0ull);

    gbar(bar, 0);

    const int skc = tid >> 3;            // staging: k within chunk (0..31)
    const int sb  = (tid & 7) * 8;       // staging: b offset in floats (0..56)
    const int hb0 = bgB * 32 + (tid & 7) * 4;   // staging: b offset in u64 units

    for (int t = 0; t < TLEN; ++t) {
        const u64* hc = &g_hx[t & 1][0][0];
        u64*       hn = &g_hx[(t + 1) & 1][0][0];

        if (tid < 64) sX[tid] = x[(size_t)(bgB * 64 + tid) * TLEN + t];
        {   // stage h chunk 0
            const u64* src = hc + (size_t)skc * 64 + hb0;
            const u64 a0 = aload(src), a1 = aload(src + 1);
            const u64 a2 = aload(src + 2), a3 = aload(src + 3);
            *(float4*)&sH[0][skc][sb]     = two2f4(a0, a1);
            *(float4*)&sH[0][skc][sb + 4] = two2f4(a2, a3);
        }
        __syncthreads();

        float4 acc[2][8];   // [j_local][b_local]; components = 4 gates. STATIC indices only.
        #pragma unroll
        for (int jl = 0; jl < 2; ++jl)
            #pragma unroll
            for (int cb = 0; cb < 8; ++cb)
                acc[jl][cb] = make_float4(0.f, 0.f, 0.f, 0.f);

        #pragma unroll 1
        for (int c = 0; c < 32; ++c) {
            const int buf = c & 1;
            u64 q0, q1, q2, q3;
            if (c < 31) {   // global->reg prefetch of chunk c+1 (sc1, via MALL)
                const u64* src = hc + (size_t)((c + 1) * 32 + skc) * 64 + hb0;
                q0 = aload(src);     q1 = aload(src + 1);
                q2 = aload(src + 2); q3 = aload(src + 3);
            }
            #pragma unroll
            for (int kk = 0; kk < 4; ++kk) {
                const int kc = kk * 8 + ks;
                const float4 w0 = ld4(&sW[jq * 2 + 0][c * 32 + kc][0]);
                const float4 w1 = ld4(&sW[jq * 2 + 1][c * 32 + kc][0]);
                const float4 hA = ld4(&sH[buf][kc][bo8 * 8]);
                const float4 hB = ld4(&sH[buf][kc][bo8 * 8 + 4]);
                FMA4(acc[0][0], hA.x, w0); FMA4(acc[0][1], hA.y, w0);
                FMA4(acc[0][2], hA.z, w0); FMA4(acc[0][3], hA.w, w0);
                FMA4(acc[0][4], hB.x, w0); FMA4(acc[0][5], hB.y, w0);
                FMA4(acc[0][6], hB.z, w0); FMA4(acc[0][7], hB.w, w0);
                FMA4(acc[1][0], hA.x, w1); FMA4(acc[1][1], hA.y, w1);
                FMA4(acc[1][2], hA.z, w1); FMA4(acc[1][3], hA.w, w1);
                FMA4(acc[1][4], hB.x, w1); FMA4(acc[1][5], hB.y, w1);
                FMA4(acc[1][6], hB.z, w1); FMA4(acc[1][7], hB.w, w1);
            }
            if (c < 31) {   // reg->LDS for chunk c+1
                *(float4*)&sH[buf ^ 1][skc][sb]     = two2f4(q0, q1);
                *(float4*)&sH[buf ^ 1][skc][sb + 4] = two2f4(q2, q3);
            }
            __syncthreads();
        }

        // ---- butterfly over ks (lane bits 0..2): deterministic pairwise tree
        #pragma unroll
        for (int jl = 0; jl < 2; ++jl)
            #pragma unroll
            for (int cb = 0; cb < 8; ++cb) {
                float4& v = acc[jl][cb];
                v.x += __shfl_xor(v.x, 1); v.y += __shfl_xor(v.y, 1);
                v.z += __shfl_xor(v.z, 1); v.w += __shfl_xor(v.w, 1);
                v.x += __shfl_xor(v.x, 2); v.y += __shfl_xor(v.y, 2);
                v.z += __shfl_xor(v.z, 2); v.w += __shfl_xor(v.w, 2);
                v.x += __shfl_xor(v.x, 4); v.y += __shfl_xor(v.y, 4);
                v.z += __shfl_xor(v.z, 4); v.w += __shfl_xor(v.w, 4);
            }

        // ---- epilogue: 8 static branches; register indices literal ----
#define EPI(K)                                                                              \
        if (ks == (K)) {                                                                    \
            const int cbK = ((K) & 3) * 2;                                                  \
            float4 q0 = acc[(K) >> 2][((K) & 3) * 2 + 0];                                   \
            float4 q1 = acc[(K) >> 2][((K) & 3) * 2 + 1];                                   \
            const float xa = sX[bo8 * 8 + cbK];                                             \
            const float xb = sX[bo8 * 8 + cbK + 1];                                         \
            FMA4(q0, xa, wx4); FMA4(q1, xb, wx4);                                           \
            q0.x += b4.x; q0.y += b4.y; q0.z += b4.z; q0.w += b4.w;                         \
            q1.x += b4.x; q1.y += b4.y; q1.z += b4.z; q1.w += b4.w;                         \
            const float g0 = tanhf(q0.x);                                                   \
            const float i0 = 1.f / (1.f + expf(-q0.y));                                     \
            const float f0 = 1.f / (1.f + expf(-q0.z));                                     \
            const float o0 = 1.f / (1.f + expf(-q0.w));                                     \
            c0 = g0 * i0 + c0 * f0;                                                         \
            const float hv0 = tanhf(c0) * o0;                                               \
            const float g1 = tanhf(q1.x);                                                   \
            const float i1 = 1.f / (1.f + expf(-q1.y));                                     \
            const float f1 = 1.f / (1.f + expf(-q1.z));                                     \
            const float o1 = 1.f / (1.f + expf(-q1.w));                                     \
            c1 = g1 * i1 + c1 * f1;                                                         \
            const float hv1 = tanhf(c1) * o1;                                               \
            astore(hn + (size_t)jc * 64 + bgB * 32 + bo8 * 4 + ((K) & 3),                   \
                   f2toU(hv0, hv1));                                                        \
        }
        EPI(0) EPI(1) EPI(2) EPI(3) EPI(4) EPI(5) EPI(6) EPI(7)
#undef EPI

        gbar(bar, t + 1);
    } // t

    // ---- final projection: out = h_final @ W_ph + bias_p (final h in buf 0) ----
    if (blockIdx.x < BATCH) {
        const int b = blockIdx.x;
        float part[CDIM];
        #pragma unroll
        for (int c2 = 0; c2 < CDIM; ++c2) part[c2] = 0.f;
        for (int k = tid; k < HDIM; k += NT) {
            const float2 hv2 = u2f2(aload(&g_hx[0][k][b >> 1]));
            const float hvv = (b & 1) ? hv2.y : hv2.x;
            #pragma unroll
            for (int c2 = 0; c2 < CDIM; ++c2)
                part[c2] = fmaf(hvv, Wph[(size_t)k * CDIM + c2], part[c2]);
        }
        float* red = (float*)&sH[0][0][0];   // reuse dead staging LDS
        #pragma unroll
        for (int c2 = 0; c2 < CDIM; ++c2) red[tid * 12 + c2] = part[c2];
        __syncthreads();
        for (int s = NT / 2; s > 0; s >>= 1) {
            if (tid < s) {
                #pragma unroll
                for (int c2 = 0; c2 < CDIM; ++c2)
                    red[tid * 12 + c2] += red[(tid + s) * 12 + c2];
            }
            __syncthreads();
        }
        if (tid < CDIM) out[(size_t)b * CDIM + tid] = red[tid] + bp[tid];
    }
}

extern "C" void kernel_launch(void* const* d_in, const int* in_sizes, int n_in,
                              void* d_out, int out_size, void* d_ws, size_t ws_size,
                              hipStream_t stream) {
    const float* x   = (const float*)d_in[0];
    const float* Wgx = (const float*)d_in[1];
    const float* Wgh = (const float*)d_in[2];
    const float* bg  = (const float*)d_in[3];
    const float* Wix = (const float*)d_in[4];
    const float* Wih = (const float*)d_in[5];
    const float* bi  = (const float*)d_in[6];
    const float* Wfx = (const float*)d_in[7];
    const float* Wfh = (const float*)d_in[8];
    const float* bf  = (const float*)d_in[9];
    const float* Wox = (const float*)d_in[10];
    const float* Woh = (const float*)d_in[11];
    const float* bo  = (const float*)d_in[12];
    const float* Wph = (const float*)d_in[13];
    const float* bp  = (const float*)d_in[14];
    u32* bar = (u32*)d_ws;                 // TLEN+2 barrier slots
    float* out = (float*)d_out;

    hipMemsetAsync(d_ws, 0, (TLEN + 2) * sizeof(u32), stream);   // capturable node

    void* args[] = {&x, &Wgx, &Wgh, &bg, &Wix, &Wih, &bi, &Wfx, &Wfh, &bf,
                    &Wox, &Woh, &bo, &Wph, &bp, &bar, &out};
    hipError_t rc = hipLaunchCooperativeKernel((void*)lstm_fused, dim3(NWG), dim3(NT),
                                               args, 0, stream);
    if (rc != hipSuccess) {
        // Custom barrier needs no cooperative-runtime support; 256 blocks at
        // 1 block/CU are fully co-resident under a regular launch too.
        lstm_fused<<<dim3(NWG), dim3(NT), 0, stream>>>(
            x, Wgx, Wgh, bg, Wix, Wih, bi, Wfx, Wfh, bf,
            Wox, Woh, bo, Wph, bp, bar, out);
    }
}

// Round 7
// 12790.340 us; speedup vs baseline: 6.1964x; 1.0025x over previous
//
#include <hip/hip_runtime.h>
#include <cmath>

#define BATCH 128
#define TLEN  256
#define HDIM  1024
#define CDIM  10
#define NT    256
#define NWG   256

typedef unsigned long long u64;
typedef unsigned int u32;

// h state, double buffered, k-major, u64 = 2 packed floats: g_hx[buf][j][b/2].
// WRITES: relaxed agent-scope sc1 (write-through -> L2 never dirty, value at
// MALL before the barrier). READS: plain cached loads (XCD L2 shared across
// the 32 blocks of an XCD), made safe by an acquire-agent fence (buffer_inv
// sc1, no wbl2) after each grid barrier: post-inv fills are fresh from MALL.
__device__ u64 g_hx[2][HDIM][BATCH / 2];

__device__ __forceinline__ float4 ld4(const float* p) { return *(const float4*)p; }

__device__ __forceinline__ void astore(u64* p, u64 v) {
    __hip_atomic_store(p, v, __ATOMIC_RELAXED, __HIP_MEMORY_SCOPE_AGENT);
}
__device__ __forceinline__ float4 two2f4(u64 a, u64 b) {
    u64 t[2] = {a, b}; float4 f; __builtin_memcpy(&f, t, 16); return f;
}
__device__ __forceinline__ u64 f2toU(float a, float b) {
    float2 f = make_float2(a, b); u64 v; __builtin_memcpy(&v, &f, 8); return v;
}
__device__ __forceinline__ float2 u2f2(u64 v) {
    float2 f; __builtin_memcpy(&f, &v, 8); return f;
}

// Grid barrier. __syncthreads drains vmcnt(0) => this block's sc1 h-stores are
// at the coherence point before arrive. After release, EVERY wave issues an
// acquire-agent fence (buffer_inv, clean-L2 invalidate) so its subsequent
// cached h reads cannot see pre-barrier L2 copies. Spin bounded: bugs degrade
// to wrong answers, never hangs.
__device__ __forceinline__ void gbar(u32* ctr, int slot) {
    __syncthreads();
    if (threadIdx.x == 0) {
        __hip_atomic_fetch_add(&ctr[slot], 1u, __ATOMIC_RELAXED, __HIP_MEMORY_SCOPE_AGENT);
        int guard = 0;
        while (__hip_atomic_load(&ctr[slot], __ATOMIC_RELAXED, __HIP_MEMORY_SCOPE_AGENT) < NWG
               && ++guard < (1 << 22)) {
            __builtin_amdgcn_s_sleep(2);
        }
    }
    __syncthreads();
    __builtin_amdgcn_fence(__ATOMIC_ACQUIRE, "agent");   // buffer_inv sc1 only
}

#define FMA4(d, s, v) do { (d).x = fmaf((s), (v).x, (d).x); (d).y = fmaf((s), (v).y, (d).y); \
                           (d).z = fmaf((s), (v).z, (d).z); (d).w = fmaf((s), (v).w, (d).w); } while (0)

// Block: 8 j x 64 b. Thread: wave jq -> j pair; lane = bo8*8+ks. Gates in
// float4 components (x=g,y=i,z=f,w=o). All register-array indices static
// (round-3 lesson: dynamic index -> scratch demotion -> HBM flood).
__global__ void __launch_bounds__(NT, 1)
lstm_fused(const float* __restrict__ x,
           const float* __restrict__ Wgx, const float* __restrict__ Wgh, const float* __restrict__ bg,
           const float* __restrict__ Wix, const float* __restrict__ Wih, const float* __restrict__ bi,
           const float* __restrict__ Wfx, const float* __restrict__ Wfh, const float* __restrict__ bf,
           const float* __restrict__ Wox, const float* __restrict__ Woh, const float* __restrict__ bo,
           const float* __restrict__ Wph, const float* __restrict__ bp,
           u32* __restrict__ bar, float* __restrict__ out)
{
    __shared__ float sW[8][HDIM][4];   // [j_local][k][gate], 128 KB, persistent
    __shared__ float sH[2][32][68];    // [buf][k_chunk][b_local]
    __shared__ float sX[64];

    const int tid  = threadIdx.x;
    const int jq   = tid >> 6;
    const int lane = tid & 63;
    const int ks   = lane & 7;
    const int bo8  = lane >> 3;
    const int rgB  = blockIdx.x >> 1;   // j in [8*rgB, 8*rgB+8)
    const int bgB  = blockIdx.x & 1;    // b in [64*bgB, 64*bgB+64)

    // ---- stage W once, gate-interleaved ----
    {
        auto stageW = [&](const float* Wsrc, int g) {
            #pragma unroll
            for (int it = 0; it < 8; ++it) {
                const float4 v = ld4(Wsrc + (size_t)(rgB * 8 + it) * HDIM + tid * 4);
                sW[it][tid * 4 + 0][g] = v.x;
                sW[it][tid * 4 + 1][g] = v.y;
                sW[it][tid * 4 + 2][g] = v.z;
                sW[it][tid * 4 + 3][g] = v.w;
            }
        };
        stageW(Wgh, 0); stageW(Wih, 1); stageW(Wfh, 2); stageW(Woh, 3);
    }

    // thread's 2 cells: (j = rgB*8 + jq*2 + (ks>>2), b = bgB*64 + bo8*8 + (ks&3)*2 + {0,1})
    const int jc = rgB * 8 + jq * 2 + (ks >> 2);
    const float4 wx4 = make_float4(Wgx[jc], Wix[jc], Wfx[jc], Wox[jc]);
    const float4 b4  = make_float4(bg[jc], bi[jc], bf[jc], bo[jc]);
    float c0 = 0.f, c1 = 0.f;

    // zero h0: 256 blocks x 256 threads x 1 u64 covers g_hx[0]
    astore(&g_hx[0][0][0] + (size_t)blockIdx.x * 256 + tid, 0ull);

    gbar(bar, 0);

    const int skc = tid >> 3;                   // staging: k within chunk (0..31)
    const int sb  = (tid & 7) * 8;              // staging: b offset in floats
    const int hb0 = bgB * 32 + (tid & 7) * 4;   // staging: b offset in u64 units

    for (int t = 0; t < TLEN; ++t) {
        const u64* hc = &g_hx[t & 1][0][0];
        u64*       hn = &g_hx[(t + 1) & 1][0][0];

        if (tid < 64) sX[tid] = x[(size_t)(bgB * 64 + tid) * TLEN + t];
        {   // stage h chunk 0 (plain cached loads)
            const u64* src = hc + (size_t)skc * 64 + hb0;
            const u64 a0 = src[0], a1 = src[1], a2 = src[2], a3 = src[3];
            *(float4*)&sH[0][skc][sb]     = two2f4(a0, a1);
            *(float4*)&sH[0][skc][sb + 4] = two2f4(a2, a3);
        }
        __syncthreads();

        float4 acc[2][8];   // [j_local][b_local]; components = 4 gates. STATIC indices only.
        #pragma unroll
        for (int jl = 0; jl < 2; ++jl)
            #pragma unroll
            for (int cb = 0; cb < 8; ++cb)
                acc[jl][cb] = make_float4(0.f, 0.f, 0.f, 0.f);

        #pragma unroll 1
        for (int c = 0; c < 32; ++c) {
            const int buf = c & 1;
            u64 q0, q1, q2, q3;
            if (c < 31) {   // global->reg prefetch of chunk c+1 (L2-cached)
                const u64* src = hc + (size_t)((c + 1) * 32 + skc) * 64 + hb0;
                q0 = src[0]; q1 = src[1]; q2 = src[2]; q3 = src[3];
            }
            #pragma unroll
            for (int kk = 0; kk < 4; ++kk) {
                const int kc = kk * 8 + ks;
                const float4 w0 = ld4(&sW[jq * 2 + 0][c * 32 + kc][0]);
                const float4 w1 = ld4(&sW[jq * 2 + 1][c * 32 + kc][0]);
                const float4 hA = ld4(&sH[buf][kc][bo8 * 8]);
                const float4 hB = ld4(&sH[buf][kc][bo8 * 8 + 4]);
                FMA4(acc[0][0], hA.x, w0); FMA4(acc[0][1], hA.y, w0);
                FMA4(acc[0][2], hA.z, w0); FMA4(acc[0][3], hA.w, w0);
                FMA4(acc[0][4], hB.x, w0); FMA4(acc[0][5], hB.y, w0);
                FMA4(acc[0][6], hB.z, w0); FMA4(acc[0][7], hB.w, w0);
                FMA4(acc[1][0], hA.x, w1); FMA4(acc[1][1], hA.y, w1);
                FMA4(acc[1][2], hA.z, w1); FMA4(acc[1][3], hA.w, w1);
                FMA4(acc[1][4], hB.x, w1); FMA4(acc[1][5], hB.y, w1);
                FMA4(acc[1][6], hB.z, w1); FMA4(acc[1][7], hB.w, w1);
            }
            if (c < 31) {   // reg->LDS for chunk c+1
                *(float4*)&sH[buf ^ 1][skc][sb]     = two2f4(q0, q1);
                *(float4*)&sH[buf ^ 1][skc][sb + 4] = two2f4(q2, q3);
            }
            __syncthreads();
        }

        // ---- butterfly over ks (lane bits 0..2): deterministic pairwise tree
        #pragma unroll
        for (int jl = 0; jl < 2; ++jl)
            #pragma unroll
            for (int cb = 0; cb < 8; ++cb) {
                float4& v = acc[jl][cb];
                v.x += __shfl_xor(v.x, 1); v.y += __shfl_xor(v.y, 1);
                v.z += __shfl_xor(v.z, 1); v.w += __shfl_xor(v.w, 1);
                v.x += __shfl_xor(v.x, 2); v.y += __shfl_xor(v.y, 2);
                v.z += __shfl_xor(v.z, 2); v.w += __shfl_xor(v.w, 2);
                v.x += __shfl_xor(v.x, 4); v.y += __shfl_xor(v.y, 4);
                v.z += __shfl_xor(v.z, 4); v.w += __shfl_xor(v.w, 4);
            }

        // ---- epilogue: 8 static branches; register indices literal ----
#define EPI(K)                                                                              \
        if (ks == (K)) {                                                                    \
            const int cbK = ((K) & 3) * 2;                                                  \
            float4 q0 = acc[(K) >> 2][((K) & 3) * 2 + 0];                                   \
            float4 q1 = acc[(K) >> 2][((K) & 3) * 2 + 1];                                   \
            const float xa = sX[bo8 * 8 + cbK];                                             \
            const float xb = sX[bo8 * 8 + cbK + 1];                                         \
            FMA4(q0, xa, wx4); FMA4(q1, xb, wx4);                                           \
            q0.x += b4.x; q0.y += b4.y; q0.z += b4.z; q0.w += b4.w;                         \
            q1.x += b4.x; q1.y += b4.y; q1.z += b4.z; q1.w += b4.w;                         \
            const float g0 = tanhf(q0.x);                                                   \
            const float i0 = 1.f / (1.f + expf(-q0.y));                                     \
            const float f0 = 1.f / (1.f + expf(-q0.z));                                     \
            const float o0 = 1.f / (1.f + expf(-q0.w));                                     \
            c0 = g0 * i0 + c0 * f0;                                                         \
            const float hv0 = tanhf(c0) * o0;                                               \
            const float g1 = tanhf(q1.x);                                                   \
            const float i1 = 1.f / (1.f + expf(-q1.y));                                     \
            const float f1 = 1.f / (1.f + expf(-q1.z));                                     \
            const float o1 = 1.f / (1.f + expf(-q1.w));                                     \
            c1 = g1 * i1 + c1 * f1;                                                         \
            const float hv1 = tanhf(c1) * o1;                                               \
            astore(hn + (size_t)jc * 64 + bgB * 32 + bo8 * 4 + ((K) & 3),                   \
                   f2toU(hv0, hv1));                                                        \
        }
        EPI(0) EPI(1) EPI(2) EPI(3) EPI(4) EPI(5) EPI(6) EPI(7)
#undef EPI

        gbar(bar, t + 1);
    } // t

    // ---- final projection: out = h_final @ W_ph + bias_p (final h in buf 0) ----
    if (blockIdx.x < BATCH) {
        const int b = blockIdx.x;
        float part[CDIM];
        #pragma unroll
        for (int c2 = 0; c2 < CDIM; ++c2) part[c2] = 0.f;
        for (int k = tid; k < HDIM; k += NT) {
            const float2 hv2 = u2f2(g_hx[0][k][b >> 1]);   // post-gbar: fresh
            const float hvv = (b & 1) ? hv2.y : hv2.x;
            #pragma unroll
            for (int c2 = 0; c2 < CDIM; ++c2)
                part[c2] = fmaf(hvv, Wph[(size_t)k * CDIM + c2], part[c2]);
        }
        float* red = (float*)&sH[0][0][0];   // reuse dead staging LDS
        #pragma unroll
        for (int c2 = 0; c2 < CDIM; ++c2) red[tid * 12 + c2] = part[c2];
        __syncthreads();
        for (int s = NT / 2; s > 0; s >>= 1) {
            if (tid < s) {
                #pragma unroll
                for (int c2 = 0; c2 < CDIM; ++c2)
                    red[tid * 12 + c2] += red[(tid + s) * 12 + c2];
            }
            __syncthreads();
        }
        if (tid < CDIM) out[(size_t)b * CDIM + tid] = red[tid] + bp[tid];
    }
}

extern "C" void kernel_launch(void* const* d_in, const int* in_sizes, int n_in,
                              void* d_out, int out_size, void* d_ws, size_t ws_size,
                              hipStream_t stream) {
    const float* x   = (const float*)d_in[0];
    const float* Wgx = (const float*)d_in[1];
    const float* Wgh = (const float*)d_in[2];
    const float* bg  = (const float*)d_in[3];
    const float* Wix = (const float*)d_in[4];
    const float* Wih = (const float*)d_in[5];
    const float* bi  = (const float*)d_in[6];
    const float* Wfx = (const float*)d_in[7];
    const float* Wfh = (const float*)d_in[8];
    const float* bf  = (const float*)d_in[9];
    const float* Wox = (const float*)d_in[10];
    const float* Woh = (const float*)d_in[11];
    const float* bo  = (const float*)d_in[12];
    const float* Wph = (const float*)d_in[13];
    const float* bp  = (const float*)d_in[14];
    u32* bar = (u32*)d_ws;                 // TLEN+2 barrier slots
    float* out = (float*)d_out;

    hipMemsetAsync(d_ws, 0, (TLEN + 2) * sizeof(u32), stream);   // capturable node

    void* args[] = {&x, &Wgx, &Wgh, &bg, &Wix, &Wih, &bi, &Wfx, &Wfh, &bf,
                    &Wox, &Woh, &bo, &Wph, &bp, &bar, &out};
    hipError_t rc = hipLaunchCooperativeKernel((void*)lstm_fused, dim3(NWG), dim3(NT),
                                               args, 0, stream);
    if (rc != hipSuccess) {
        // Custom barrier needs no cooperative-runtime support; 256 blocks at
        // 1 block/CU are fully co-resident under a regular launch too.
        lstm_fused<<<dim3(NWG), dim3(NT), 0, stream>>>(
            x, Wgx, Wgh, bg, Wix, Wih, bi, Wfx, Wfh, bf,
            Wox, Woh, bo, Wph, bp, bar, out);
    }
}

// Round 8
// 11268.250 us; speedup vs baseline: 7.0334x; 1.1351x over previous
//
#include <hip/hip_runtime.h>
#include <cmath>

#define BATCH 128
#define TLEN  256
#define HDIM  1024
#define CDIM  10
#define NT    512
#define NWG   256

typedef unsigned long long u64;
typedef unsigned int u32;

// h state, double buffered, k-major, u64 = 2 packed floats: g_hx[buf][j][b/2].
// WRITES: relaxed agent-scope sc1 (write-through -> L2 never dirty). READS:
// plain cached loads, made safe by acquire-agent fence after each grid barrier.
__device__ u64 g_hx[2][HDIM][BATCH / 2];

__device__ __forceinline__ float4 ld4(const float* p) { return *(const float4*)p; }

__device__ __forceinline__ void astore(u64* p, u64 v) {
    __hip_atomic_store(p, v, __ATOMIC_RELAXED, __HIP_MEMORY_SCOPE_AGENT);
}
__device__ __forceinline__ float4 two2f4(u64 a, u64 b) {
    u64 t[2] = {a, b}; float4 f; __builtin_memcpy(&f, t, 16); return f;
}
__device__ __forceinline__ u64 f2toU(float a, float b) {
    float2 f = make_float2(a, b); u64 v; __builtin_memcpy(&v, &f, 8); return v;
}
__device__ __forceinline__ float2 u2f2(u64 v) {
    float2 f; __builtin_memcpy(&f, &v, 8); return f;
}

// Grid barrier (round-6/7 proven). __syncthreads drains vmcnt(0) => sc1
// h-stores are at the coherence point before arrive. Acquire fence after:
// buffer_inv only (L2 never dirty). Bounded spin: bugs -> wrong, never hang.
__device__ __forceinline__ void gbar(u32* ctr, int slot) {
    __syncthreads();
    if (threadIdx.x == 0) {
        __hip_atomic_fetch_add(&ctr[slot], 1u, __ATOMIC_RELAXED, __HIP_MEMORY_SCOPE_AGENT);
        int guard = 0;
        while (__hip_atomic_load(&ctr[slot], __ATOMIC_RELAXED, __HIP_MEMORY_SCOPE_AGENT) < NWG
               && ++guard < (1 << 22)) {
            __builtin_amdgcn_s_sleep(2);
        }
    }
    __syncthreads();
    __builtin_amdgcn_fence(__ATOMIC_ACQUIRE, "agent");
}

#define FMA4(d, s, v) do { (d).x = fmaf((s), (v).x, (d).x); (d).y = fmaf((s), (v).y, (d).y); \
                           (d).z = fmaf((s), (v).z, (d).z); (d).w = fmaf((s), (v).w, (d).w); } while (0)

// Block: 8 j x 64 b. 8 waves: wave = jq*2 + kh. Wave (jq,kh) computes the
// 2j x 64b tile over k-subset {c*32 + kk*16 + kh*8 + ks}. Intra-wave butterfly
// over ks, then cross-kh reduction through LDS scratch sS. 2 waves/SIMD ->
// latency overlap (round-7 lesson: at 1 wave/SIMD all stalls ADD).
__global__ void __launch_bounds__(NT, 1)
lstm_fused(const float* __restrict__ x,
           const float* __restrict__ Wgx, const float* __restrict__ Wgh, const float* __restrict__ bg,
           const float* __restrict__ Wix, const float* __restrict__ Wih, const float* __restrict__ bi,
           const float* __restrict__ Wfx, const float* __restrict__ Wfh, const float* __restrict__ bf,
           const float* __restrict__ Wox, const float* __restrict__ Woh, const float* __restrict__ bo,
           const float* __restrict__ Wph, const float* __restrict__ bp,
           u32* __restrict__ bar, float* __restrict__ out)
{
    __shared__ float  sW[8][HDIM][4];   // [j_local][k][gate], 128 KB, persistent
    __shared__ float  sH[2][32][68];    // [buf][k_chunk][b_local], 17 KB
    __shared__ float4 sS[4][64][2];     // cross-kh partials, 8 KB
    __shared__ float  sX[64];
    // total 156.9 KB < 160 KB

    const int tid  = threadIdx.x;
    const int wave = tid >> 6;          // 0..7
    const int jq   = wave >> 1;         // j-pair index (0..3)
    const int kh   = wave & 1;          // k-half within chunk
    const int lane = tid & 63;
    const int ks   = lane & 7;
    const int bo8  = lane >> 3;
    const int rgB  = blockIdx.x >> 1;   // j in [8*rgB, 8*rgB+8)
    const int bgB  = blockIdx.x & 1;    // b in [64*bgB, 64*bgB+64)

    // ---- stage W once, gate-interleaved (512 threads: 2 rows per pass) ----
    {
        auto stageW = [&](const float* Wsrc, int g) {
            #pragma unroll
            for (int it = 0; it < 4; ++it) {
                const int row = it * 2 + (tid >> 8);     // 0..7
                const int c4  = tid & 255;               // float4 column
                const float4 v = ld4(Wsrc + (size_t)(rgB * 8 + row) * HDIM + c4 * 4);
                sW[row][c4 * 4 + 0][g] = v.x;
                sW[row][c4 * 4 + 1][g] = v.y;
                sW[row][c4 * 4 + 2][g] = v.z;
                sW[row][c4 * 4 + 3][g] = v.w;
            }
        };
        stageW(Wgh, 0); stageW(Wih, 1); stageW(Wfh, 2); stageW(Woh, 3);
    }

    // epilogue cells (kh==0 waves only): j = rgB*8 + jq*2 + (ks>>2),
    // b = bgB*64 + bo8*8 + (ks&3)*2 + {0,1}
    const int jc = rgB * 8 + jq * 2 + (ks >> 2);
    const float4 wx4 = make_float4(Wgx[jc], Wix[jc], Wfx[jc], Wox[jc]);
    const float4 b4  = make_float4(bg[jc], bi[jc], bf[jc], bo[jc]);
    float c0 = 0.f, c1 = 0.f;

    // zero h0 (threads 0..255 of each block cover g_hx[0])
    if (tid < 256)
        astore(&g_hx[0][0][0] + (size_t)blockIdx.x * 256 + tid, 0ull);

    gbar(bar, 0);

    const int skc = tid >> 4;                   // staging: k within chunk (0..31)
    const int sb  = (tid & 15) * 4;             // staging: b offset in floats
    const int hb0 = bgB * 32 + (tid & 15) * 2;  // staging: b offset in u64 units

    for (int t = 0; t < TLEN; ++t) {
        const u64* hc = &g_hx[t & 1][0][0];
        u64*       hn = &g_hx[(t + 1) & 1][0][0];

        if (tid < 64) sX[tid] = x[(size_t)(bgB * 64 + tid) * TLEN + t];
        {   // stage h chunk 0 (1 float4 per thread)
            const u64* src = hc + (size_t)skc * 64 + hb0;
            *(float4*)&sH[0][skc][sb] = two2f4(src[0], src[1]);
        }
        __syncthreads();

        float4 acc[2][8];   // [j_local][b_in_octet]; components = 4 gates. STATIC indices only.
        #pragma unroll
        for (int jl = 0; jl < 2; ++jl)
            #pragma unroll
            for (int cb = 0; cb < 8; ++cb)
                acc[jl][cb] = make_float4(0.f, 0.f, 0.f, 0.f);

        #pragma unroll 1
        for (int c = 0; c < 32; ++c) {
            const int buf = c & 1;
            u64 q0, q1;
            if (c < 31) {   // global->reg prefetch of chunk c+1
                const u64* src = hc + (size_t)((c + 1) * 32 + skc) * 64 + hb0;
                q0 = src[0]; q1 = src[1];
            }
            #pragma unroll
            for (int kk = 0; kk < 2; ++kk) {
                const int kc = kk * 16 + kh * 8 + ks;
                const float4 w0 = ld4(&sW[jq * 2 + 0][c * 32 + kc][0]);
                const float4 w1 = ld4(&sW[jq * 2 + 1][c * 32 + kc][0]);
                const float4 hA = ld4(&sH[buf][kc][bo8 * 8]);
                const float4 hB = ld4(&sH[buf][kc][bo8 * 8 + 4]);
                FMA4(acc[0][0], hA.x, w0); FMA4(acc[0][1], hA.y, w0);
                FMA4(acc[0][2], hA.z, w0); FMA4(acc[0][3], hA.w, w0);
                FMA4(acc[0][4], hB.x, w0); FMA4(acc[0][5], hB.y, w0);
                FMA4(acc[0][6], hB.z, w0); FMA4(acc[0][7], hB.w, w0);
                FMA4(acc[1][0], hA.x, w1); FMA4(acc[1][1], hA.y, w1);
                FMA4(acc[1][2], hA.z, w1); FMA4(acc[1][3], hA.w, w1);
                FMA4(acc[1][4], hB.x, w1); FMA4(acc[1][5], hB.y, w1);
                FMA4(acc[1][6], hB.z, w1); FMA4(acc[1][7], hB.w, w1);
            }
            if (c < 31) {   // reg->LDS for chunk c+1
                *(float4*)&sH[buf ^ 1][skc][sb] = two2f4(q0, q1);
            }
            __syncthreads();
        }

        // ---- butterfly over ks (lane bits 0..2) ----
        #pragma unroll
        for (int jl = 0; jl < 2; ++jl)
            #pragma unroll
            for (int cb = 0; cb < 8; ++cb) {
                float4& v = acc[jl][cb];
                v.x += __shfl_xor(v.x, 1); v.y += __shfl_xor(v.y, 1);
                v.z += __shfl_xor(v.z, 1); v.w += __shfl_xor(v.w, 1);
                v.x += __shfl_xor(v.x, 2); v.y += __shfl_xor(v.y, 2);
                v.z += __shfl_xor(v.z, 2); v.w += __shfl_xor(v.w, 2);
                v.x += __shfl_xor(v.x, 4); v.y += __shfl_xor(v.y, 4);
                v.z += __shfl_xor(v.z, 4); v.w += __shfl_xor(v.w, 4);
            }

        // ---- select this lane's 2 cells (static indices via 8 branches) ----
        float4 q0 = make_float4(0.f, 0.f, 0.f, 0.f);
        float4 q1 = make_float4(0.f, 0.f, 0.f, 0.f);
#define SEL(K)                                                          \
        if (ks == (K)) {                                                \
            q0 = acc[(K) >> 2][((K) & 3) * 2 + 0];                      \
            q1 = acc[(K) >> 2][((K) & 3) * 2 + 1];                      \
        }
        SEL(0) SEL(1) SEL(2) SEL(3) SEL(4) SEL(5) SEL(6) SEL(7)
#undef SEL

        // ---- cross-kh reduction through LDS scratch ----
        if (kh == 1) {
            sS[jq][lane][0] = q0;
            sS[jq][lane][1] = q1;
        }
        __syncthreads();

        if (kh == 0) {
            const float4 p0 = sS[jq][lane][0];
            const float4 p1 = sS[jq][lane][1];
            q0.x += p0.x; q0.y += p0.y; q0.z += p0.z; q0.w += p0.w;
            q1.x += p1.x; q1.y += p1.y; q1.z += p1.z; q1.w += p1.w;

            const int cbK = (ks & 3) * 2;
            const float xa = sX[bo8 * 8 + cbK];
            const float xb = sX[bo8 * 8 + cbK + 1];
            FMA4(q0, xa, wx4); FMA4(q1, xb, wx4);
            q0.x += b4.x; q0.y += b4.y; q0.z += b4.z; q0.w += b4.w;
            q1.x += b4.x; q1.y += b4.y; q1.z += b4.z; q1.w += b4.w;

            const float g0 = tanhf(q0.x);
            const float i0 = 1.f / (1.f + expf(-q0.y));
            const float f0 = 1.f / (1.f + expf(-q0.z));
            const float o0 = 1.f / (1.f + expf(-q0.w));
            c0 = g0 * i0 + c0 * f0;
            const float hv0 = tanhf(c0) * o0;

            const float g1 = tanhf(q1.x);
            const float i1 = 1.f / (1.f + expf(-q1.y));
            const float f1 = 1.f / (1.f + expf(-q1.z));
            const float o1 = 1.f / (1.f + expf(-q1.w));
            c1 = g1 * i1 + c1 * f1;
            const float hv1 = tanhf(c1) * o1;

            astore(hn + (size_t)jc * 64 + bgB * 32 + bo8 * 4 + (ks & 3),
                   f2toU(hv0, hv1));
        }

        gbar(bar, t + 1);
    } // t

    // ---- final projection: out = h_final @ W_ph + bias_p (final h in buf 0) ----
    if (blockIdx.x < BATCH) {
        const int b = blockIdx.x;
        float part[CDIM];
        #pragma unroll
        for (int c2 = 0; c2 < CDIM; ++c2) part[c2] = 0.f;
        for (int k = tid; k < HDIM; k += NT) {
            const float2 hv2 = u2f2(g_hx[0][k][b >> 1]);   // post-gbar: fresh
            const float hvv = (b & 1) ? hv2.y : hv2.x;
            #pragma unroll
            for (int c2 = 0; c2 < CDIM; ++c2)
                part[c2] = fmaf(hvv, Wph[(size_t)k * CDIM + c2], part[c2]);
        }
        float* red = (float*)&sW[0][0][0];   // reuse dead W LDS (24 KB needed)
        #pragma unroll
        for (int c2 = 0; c2 < CDIM; ++c2) red[tid * 12 + c2] = part[c2];
        __syncthreads();
        for (int s = NT / 2; s > 0; s >>= 1) {
            if (tid < s) {
                #pragma unroll
                for (int c2 = 0; c2 < CDIM; ++c2)
                    red[tid * 12 + c2] += red[(tid + s) * 12 + c2];
            }
            __syncthreads();
        }
        if (tid < CDIM) out[(size_t)b * CDIM + tid] = red[tid] + bp[tid];
    }
}

extern "C" void kernel_launch(void* const* d_in, const int* in_sizes, int n_in,
                              void* d_out, int out_size, void* d_ws, size_t ws_size,
                              hipStream_t stream) {
    const float* x   = (const float*)d_in[0];
    const float* Wgx = (const float*)d_in[1];
    const float* Wgh = (const float*)d_in[2];
    const float* bg  = (const float*)d_in[3];
    const float* Wix = (const float*)d_in[4];
    const float* Wih = (const float*)d_in[5];
    const float* bi  = (const float*)d_in[6];
    const float* Wfx = (const float*)d_in[7];
    const float* Wfh = (const float*)d_in[8];
    const float* bf  = (const float*)d_in[9];
    const float* Wox = (const float*)d_in[10];
    const float* Woh = (const float*)d_in[11];
    const float* bo  = (const float*)d_in[12];
    const float* Wph = (const float*)d_in[13];
    const float* bp  = (const float*)d_in[14];
    u32* bar = (u32*)d_ws;                 // TLEN+2 barrier slots
    float* out = (float*)d_out;

    hipMemsetAsync(d_ws, 0, (TLEN + 2) * sizeof(u32), stream);   // capturable node

    void* args[] = {&x, &Wgx, &Wgh, &bg, &Wix, &Wih, &bi, &Wfx, &Wfh, &bf,
                    &Wox, &Woh, &bo, &Wph, &bp, &bar, &out};
    hipError_t rc = hipLaunchCooperativeKernel((void*)lstm_fused, dim3(NWG), dim3(NT),
                                               args, 0, stream);
    if (rc != hipSuccess) {
        // Custom barrier needs no cooperative-runtime support; 256 blocks at
        // 1 block/CU are fully co-resident under a regular launch too.
        lstm_fused<<<dim3(NWG), dim3(NT), 0, stream>>>(
            x, Wgx, Wgh, bg, Wix, Wih, bi, Wfx, Wfh, bf,
            Wox, Woh, bo, Wph, bp, bar, out);
    }
}